// Round 2
// baseline (1139.894 us; speedup 1.0000x reference)
//
#include <hip/hip_runtime.h>
#include <hip/hip_bf16.h>

#define DIN 49
#define HIN 32
#define WIN 64
#define CIN 32
#define DOUT 193
#define HOUT 256
#define WOUT 512
#define NPIX (HOUT * WOUT)      // 131072
#define NUPS (DOUT * NPIX)      // 25296896
#define NCONV (DIN * HIN * WIN) // 100352

// ---------------------------------------------------------------------------
// Kernel 1: 3x3x3 conv, 32 -> 1 channels, zero pad 1, fp32 accumulate.
// x: [32][49][32][64] f32, w: [32][3][3][3] f32, c out: [49][32][64] fp32
// ---------------------------------------------------------------------------
__global__ void conv3d_kernel(const float* __restrict__ x,
                              const float* __restrict__ w,
                              float* __restrict__ c) {
    __shared__ float ws[CIN * 27];
    for (int t = threadIdx.x; t < CIN * 27; t += blockDim.x)
        ws[t] = w[t];
    __syncthreads();

    int idx = blockIdx.x * blockDim.x + threadIdx.x;
    if (idx >= NCONV) return;
    int wq = idx % WIN;
    int t2 = idx / WIN;
    int hq = t2 % HIN;
    int dq = t2 / HIN;

    float acc = 0.f;
    for (int ci = 0; ci < CIN; ++ci) {
        const float* xb = x + ci * NCONV;
        const float* wb = ws + ci * 27;
#pragma unroll
        for (int kd = 0; kd < 3; ++kd) {
            int zd = dq + kd - 1;
            if (zd < 0 || zd >= DIN) continue;
#pragma unroll
            for (int kh = 0; kh < 3; ++kh) {
                int zh = hq + kh - 1;
                if (zh < 0 || zh >= HIN) continue;
#pragma unroll
                for (int kw = 0; kw < 3; ++kw) {
                    int zw = wq + kw - 1;
                    if (zw < 0 || zw >= WIN) continue;
                    acc += xb[(zd * HIN + zh) * WIN + zw] *
                           wb[(kd * 3 + kh) * 3 + kw];
                }
            }
        }
    }
    c[idx] = acc;
}

// ---------------------------------------------------------------------------
// Kernel 2: trilinear upsample (half-pixel centers, edge clamp), fp32 -> bf16
// c: [49][32][64] fp32 -> u: [193][256][512] bf16
// ---------------------------------------------------------------------------
__global__ void upsample_kernel(const float* __restrict__ c,
                                __hip_bfloat16* __restrict__ u) {
    int idx = blockIdx.x * blockDim.x + threadIdx.x;
    if (idx >= NUPS) return;
    int ww = idx % WOUT;
    int t = idx / WOUT;
    int hh = t % HOUT;
    int dd = t / HOUT;

    float fd = (dd + 0.5f) * (49.0f / 193.0f) - 0.5f;
    fd = fminf(fmaxf(fd, 0.f), (float)(DIN - 1));
    int d0 = (int)fd;
    int d1 = min(d0 + 1, DIN - 1);
    float ad = fd - (float)d0;

    float fh = (hh + 0.5f) * 0.125f - 0.5f;
    fh = fminf(fmaxf(fh, 0.f), (float)(HIN - 1));
    int h0 = (int)fh;
    int h1 = min(h0 + 1, HIN - 1);
    float ah = fh - (float)h0;

    float fw = (ww + 0.5f) * 0.125f - 0.5f;
    fw = fminf(fmaxf(fw, 0.f), (float)(WIN - 1));
    int w0 = (int)fw;
    int w1 = min(w0 + 1, WIN - 1);
    float aw = fw - (float)w0;

    const float* p00 = c + (d0 * HIN + h0) * WIN;
    const float* p01 = c + (d0 * HIN + h1) * WIN;
    const float* p10 = c + (d1 * HIN + h0) * WIN;
    const float* p11 = c + (d1 * HIN + h1) * WIN;

    float v00 = p00[w0] + aw * (p00[w1] - p00[w0]);
    float v01 = p01[w0] + aw * (p01[w1] - p01[w0]);
    float v10 = p10[w0] + aw * (p10[w1] - p10[w0]);
    float v11 = p11[w0] + aw * (p11[w1] - p11[w0]);
    float v0 = v00 + ah * (v01 - v00);
    float v1 = v10 + ah * (v11 - v10);
    float v = v0 + ad * (v1 - v0);
    u[idx] = __float2bfloat16(v);
}

// ---------------------------------------------------------------------------
// LGA kernel. Block = 16x16 pixel tile (256 threads, 1 thread = 1 pixel).
// Per-thread: 75 normalized guidance weights in registers (g depends only on
// pixel). Loop over d in chunks of 8; stage 10 input planes (d0-1..d0+8) of a
// 20x20 halo tile into LDS; accumulate 3-tap-in-d x 25-tap-spatial.
// MODE 0: write y volume (bf16). MODE 1: online softmin + disparity regression.
// ---------------------------------------------------------------------------
template <int MODE>
__global__ __launch_bounds__(256) void lga_kernel(
    const __hip_bfloat16* __restrict__ xin,
    const float* __restrict__ lg1,
    __hip_bfloat16* __restrict__ yout,
    float* __restrict__ dispout) {
    const int tx = threadIdx.x & 15;
    const int ty = threadIdx.x >> 4;
    const int w0p = blockIdx.x * 16;
    const int h0p = blockIdx.y * 16;
    const int wpix = w0p + tx;
    const int hpix = h0p + ty;
    const int pix = hpix * WOUT + wpix;

    // Load + L1-normalize guidance into registers (75 regs).
    float g[75];
    float asum = 0.f;
#pragma unroll
    for (int ch = 0; ch < 75; ++ch) {
        g[ch] = lg1[ch * NPIX + pix];
        asum += fabsf(g[ch]);
    }
    float inv = 1.0f / fmaxf(asum, 1e-12f);
#pragma unroll
    for (int ch = 0; ch < 75; ++ch) g[ch] *= inv;

    __shared__ float su[10 * 400]; // 10 planes x (20x20) halo tile, 16 KB

    float m = -1e30f, l = 0.f, s = 0.f;

    for (int d0 = 0; d0 < DOUT; d0 += 8) {
        __syncthreads(); // protect su from previous chunk's readers
        // Stage planes gd = d0-1 .. d0+8 (zeros outside volume/image).
        for (int t = threadIdx.x; t < 4000; t += 256) {
            int dl = t / 400;
            int rc = t - dl * 400;
            int r = rc / 20;
            int cc = rc - r * 20;
            int gd = d0 - 1 + dl;
            int gh = h0p - 2 + r;
            int gw = w0p - 2 + cc;
            float v = 0.f;
            if (gd >= 0 && gd < DOUT && gh >= 0 && gh < HOUT && gw >= 0 &&
                gw < WOUT)
                v = __bfloat162float(xin[gd * NPIX + gh * WOUT + gw]);
            su[t] = v;
        }
        __syncthreads();

        float acc[8] = {0.f, 0.f, 0.f, 0.f, 0.f, 0.f, 0.f, 0.f};
#pragma unroll
        for (int i = 0; i < 5; ++i) {
#pragma unroll
            for (int j = 0; j < 5; ++j) {
                const int base = (ty + i) * 20 + (tx + j);
                float v[10];
#pragma unroll
                for (int dl = 0; dl < 10; ++dl) v[dl] = su[dl * 400 + base];
                const float g0 = g[i * 5 + j];
                const float g1 = g[25 + i * 5 + j];
                const float g2 = g[50 + i * 5 + j];
#pragma unroll
                for (int dd = 0; dd < 8; ++dd)
                    acc[dd] += g0 * v[dd + 1] + g1 * v[dd] + g2 * v[dd + 2];
            }
        }

        if (MODE == 0) {
#pragma unroll
            for (int dd = 0; dd < 8; ++dd) {
                int d = d0 + dd;
                if (d < DOUT) yout[d * NPIX + pix] = __float2bfloat16(acc[dd]);
            }
        } else {
#pragma unroll
            for (int dd = 0; dd < 8; ++dd) {
                int d = d0 + dd;
                if (d < DOUT) {
                    float v = -acc[dd];
                    float mn = fmaxf(m, v);
                    float sc = __expf(m - mn);
                    float e = __expf(v - mn);
                    l = l * sc + e;
                    s = s * sc + e * (float)d;
                    m = mn;
                }
            }
        }
    }

    if (MODE == 1) {
        dispout[pix] = s / l;
    }
}

// ---------------------------------------------------------------------------
extern "C" void kernel_launch(void* const* d_in, const int* in_sizes, int n_in,
                              void* d_out, int out_size, void* d_ws,
                              size_t ws_size, hipStream_t stream) {
    const float* x = (const float*)d_in[0];
    const float* lg1 = (const float*)d_in[1];
    const float* cw = (const float*)d_in[2];
    float* out = (float*)d_out;

    // ws layout: c fp32 [100352] | u bf16 [25296896] | y1 bf16 [25296896]
    float* c = (float*)d_ws;
    __hip_bfloat16* u = (__hip_bfloat16*)((char*)d_ws + (size_t)NCONV * 4);
    __hip_bfloat16* y1 = u + (size_t)NUPS;

    conv3d_kernel<<<(NCONV + 255) / 256, 256, 0, stream>>>(x, cw, c);
    upsample_kernel<<<NUPS / 256, 256, 0, stream>>>(c, u);

    dim3 grid(WOUT / 16, HOUT / 16); // 32 x 16 = 512 blocks
    lga_kernel<0><<<grid, 256, 0, stream>>>(u, lg1, y1, nullptr);
    lga_kernel<1><<<grid, 256, 0, stream>>>(y1, lg1, nullptr, out);
}